// Round 3
// baseline (193.985 us; speedup 1.0000x reference)
//
#include <hip/hip_runtime.h>

#define N_NODES   50000
#define N_EDGES   800000
#define DIM       128
#define N_GRAPHS  64
#define N_CLASSES 10
#define NCHE      64                   // edge chunks (u8-safe: per-chunk count <= deg ~50)
#define CSZ       (N_EDGES / NCHE)     // 12500
#define LQ        (N_NODES / 4)        // 12500 u8-packed words (4 nodes/word)
#define WPB       64                   // words per reduce block (256 nodes)
#define NBR2      ((LQ + WPB - 1) / WPB)   // 196
#define PLACE_BPC ((CSZ + 255) / 256)      // 49
#define PLACE_BLKS (NCHE * PLACE_BPC)      // 3136
#define PRES_BLKS ((N_NODES * DIM / 8 + 255) / 256)  // 3125
#define WT_BLKS   (DIM * DIM / 256)        // 64
#define LH_HIST   (2 * NCHE)               // 128 histogram blocks
#define LH_BLKS   (LH_HIST + PRES_BLKS + WT_BLKS)  // 3317
#define NPBM      64                   // nodes per block in k_gnode (MFMA tile)
#define NBLK_NODE ((N_NODES + NPBM - 1) / NPBM)  // 782

typedef _Float16 h8 __attribute__((ext_vector_type(8)));
typedef float f4v __attribute__((ext_vector_type(4)));

// ---- per-chunk LDS histograms (u8 packed) + overlapped prescale / W^T build
__global__ __launch_bounds__(256) void k_lhist(const int* __restrict__ src,
                                               const int* __restrict__ dst,
                                               unsigned* __restrict__ Hin,
                                               unsigned* __restrict__ Hout,
                                               unsigned char* __restrict__ perm,
                                               const float* __restrict__ feat,
                                               _Float16* __restrict__ sfeat,
                                               const float* __restrict__ W,
                                               _Float16* __restrict__ Wt) {
    __shared__ unsigned L[LQ];         // 50 KB
    int blk = blockIdx.x, t = threadIdx.x;
    if (blk >= LH_HIST) {
        int q = blk - LH_HIST;
        if (q < PRES_BLKS) {
            int i = q * 256 + t;
            if (i < N_NODES * DIM / 8) {
                const float4* p = reinterpret_cast<const float4*>(feat + (size_t)i * 8);
                float4 a = p[0], qv = p[1];
                h8 r;
                r[0] = (_Float16)a.x;  r[1] = (_Float16)a.y;
                r[2] = (_Float16)a.z;  r[3] = (_Float16)a.w;
                r[4] = (_Float16)qv.x; r[5] = (_Float16)qv.y;
                r[6] = (_Float16)qv.z; r[7] = (_Float16)qv.w;
                *reinterpret_cast<h8*>(sfeat + (size_t)i * 8) = r;
            }
        } else {
            int i = (q - PRES_BLKS) * 256 + t;   // i < DIM*DIM
            int n = i >> 7, k = i & 127;
            Wt[n * DIM + k] = (_Float16)W[k * DIM + n];
        }
        return;
    }
    int c = blk & (NCHE - 1);
    int phase = blk >> 6;              // 0: dst(+perm), 1: src
    int base = c * CSZ;
    for (int w = t; w < LQ; w += 256) L[w] = 0u;
    __syncthreads();
    if (phase == 0) {
        for (int i = t; i < CSZ; i += 256) {
            int d = dst[base + i];
            int sh = (d & 3) * 8;
            unsigned old = atomicAdd(&L[d >> 2], 1u << sh);
            perm[base + i] = (unsigned char)((old >> sh) & 0xffu);
        }
        __syncthreads();
        for (int w = t; w < LQ; w += 256) Hin[(size_t)c * LQ + w] = L[w];
    } else {
        for (int i = t; i < CSZ; i += 256) {
            int s = src[base + i];
            atomicAdd(&L[s >> 2], 1u << ((s & 3) * 8));
        }
        __syncthreads();
        for (int w = t; w < LQ; w += 256) Hout[(size_t)c * LQ + w] = L[w];
    }
}

// ---- reduce: degrees/norms; Hin := per-chunk prefix; boundaries; scan p1 ----
__global__ __launch_bounds__(256) void k_reduce(unsigned* __restrict__ Hin,
                                                const unsigned* __restrict__ Hout,
                                                const int* __restrict__ gid,
                                                unsigned* __restrict__ indeg,
                                                float* __restrict__ outnorm,
                                                float* __restrict__ innorm,
                                                int* __restrict__ start,
                                                unsigned* __restrict__ row_ptr,
                                                unsigned* __restrict__ blockSums) {
    __shared__ unsigned sIn[4][WPB];
    __shared__ unsigned sOut[4][WPB];
    __shared__ unsigned sS[WPB];
    int t = threadIdx.x;
    int wl = t & (WPB - 1);
    int g  = t >> 6;
    int w  = blockIdx.x * WPB + wl;
    unsigned gs = 0, os = 0;
    int c0 = g * (NCHE / 4);
    if (w < LQ) {
        for (int c = c0; c < c0 + NCHE / 4; ++c) {
            gs += Hin[(size_t)c * LQ + w];     // u8 packed adds: no carry (deg ~50)
            os += Hout[(size_t)c * LQ + w];
        }
    }
    sIn[g][wl] = gs; sOut[g][wl] = os;
    __syncthreads();
    unsigned baseg = 0;
    for (int gg = 0; gg < 4; ++gg) if (gg < g) baseg += sIn[gg][wl];
    if (w < LQ) {
        unsigned running = baseg;
        for (int c = c0; c < c0 + NCHE / 4; ++c) {
            size_t idx = (size_t)c * LQ + w;
            unsigned word = Hin[idx];
            Hin[idx] = running;
            running += word;
        }
    }
    unsigned tot = 0, otot = 0, wtot = 0;
    if (t < WPB) {
        tot  = sIn[0][t] + sIn[1][t] + sIn[2][t] + sIn[3][t];
        otot = sOut[0][t] + sOut[1][t] + sOut[2][t] + sOut[3][t];
        wtot = (tot & 0xffu) + ((tot >> 8) & 0xffu) + ((tot >> 16) & 0xffu) + (tot >> 24);
        sS[t] = wtot;
    }
    __syncthreads();
    for (int off = 1; off < WPB; off <<= 1) {
        unsigned x = (t < WPB && t >= off) ? sS[t - off] : 0u;
        __syncthreads();
        if (t < WPB) sS[t] += x;
        __syncthreads();
    }
    if (t < WPB) {
        int ww = blockIdx.x * WPB + t;
        if (ww < LQ) {
            unsigned r0 = tot & 0xffu, r1 = (tot >> 8) & 0xffu,
                     r2 = (tot >> 16) & 0xffu, r3 = tot >> 24;
            unsigned o0 = otot & 0xffu, o1 = (otot >> 8) & 0xffu,
                     o2 = (otot >> 16) & 0xffu, o3 = otot >> 24;
            unsigned ex = sS[t] - wtot;
            int n = 4 * ww;
            row_ptr[n]     = ex;
            row_ptr[n + 1] = ex + r0;
            row_ptr[n + 2] = ex + r0 + r1;
            row_ptr[n + 3] = ex + r0 + r1 + r2;
            unsigned rr[4] = {r0, r1, r2, r3}, oo[4] = {o0, o1, o2, o3};
#pragma unroll
            for (int j = 0; j < 4; ++j) {
                indeg[n + j]   = rr[j];
                innorm[n + j]  = rsqrtf(fmaxf((float)rr[j], 1.0f));
                outnorm[n + j] = rsqrtf(fmaxf((float)oo[j], 1.0f));
                int i = n + j;
                int gq = gid[i];
                if (i == 0) {
                    for (int x2 = 0; x2 <= gq; ++x2) start[x2] = 0;
                } else {
                    int gp = gid[i - 1];
                    if (gp != gq)
                        for (int x2 = gp + 1; x2 <= gq; ++x2) start[x2] = i;
                }
                if (i == N_NODES - 1)
                    for (int x2 = gq + 1; x2 <= N_GRAPHS; ++x2) start[x2] = N_NODES;
            }
        }
        if (t == WPB - 1) blockSums[blockIdx.x] = sS[WPB - 1];
    }
}

// ---- scan pass 2 + pooled zeroing ------------------------------------------
__global__ __launch_bounds__(256) void k_scan2(unsigned* __restrict__ blockSums,
                                               unsigned* __restrict__ blockOff,
                                               float* __restrict__ pooled) {
    __shared__ unsigned s[256];
    int t = threadIdx.x;
    unsigned val = (t < NBR2) ? blockSums[t] : 0u;
    s[t] = val;
    __syncthreads();
    for (int off = 1; off < 256; off <<= 1) {
        unsigned x = (t >= off) ? s[t - off] : 0u;
        __syncthreads();
        s[t] += x;
        __syncthreads();
    }
    if (t < NBR2) blockOff[t] = s[t] - val;
    float4 z = {0.f, 0.f, 0.f, 0.f};
    for (int i = t; i < N_GRAPHS * DIM / 4; i += 256)
        reinterpret_cast<float4*>(pooled)[i] = z;
}

// ---- CSR place (u16 bsrc) ---------------------------------------------------
__global__ __launch_bounds__(256) void k_place(const int* __restrict__ src,
                                               const int* __restrict__ dst,
                                               const unsigned* __restrict__ Hin,
                                               const unsigned char* __restrict__ perm,
                                               const unsigned* __restrict__ row_ptr,
                                               const unsigned* __restrict__ blockOff,
                                               unsigned short* __restrict__ bsrc) {
    int t = threadIdx.x;
    int blk = blockIdx.x;
    int c = blk / PLACE_BPC;
    int i = (blk % PLACE_BPC) * 256 + t;
    if (i < CSZ) {
        int e = c * CSZ + i;
        int d = dst[e];
        int sh = (d & 3) * 8;
        unsigned pre = (Hin[(size_t)c * LQ + (d >> 2)] >> sh) & 0xffu;
        unsigned pos = row_ptr[d] + blockOff[d >> 8] + pre + perm[e];
        bsrc[pos] = (unsigned short)src[e];
    }
}

#define CVT8(ACC_A, ACC_B, R, M) \
    ACC_A.x += (M) * (float)R[0]; ACC_A.y += (M) * (float)R[1]; \
    ACC_A.z += (M) * (float)R[2]; ACC_A.w += (M) * (float)R[3]; \
    ACC_B.x += (M) * (float)R[4]; ACC_B.y += (M) * (float)R[5]; \
    ACC_B.z += (M) * (float)R[6]; ACC_B.w += (M) * (float)R[7];

// ---- fused: gather-sum (outnorm folded) -> LDS tile -> MFMA -> mean-pool ----
// NPBM=64: 782 blocks -> ~3 blocks/CU resident (vs 1.5 at NPBM=128) for
// latency hiding; LDS 20.5 KB; acc[8] halves VGPR vs acc0/acc1.
__global__ __launch_bounds__(256) void k_gnode(const unsigned short* __restrict__ bsrc,
                                               const unsigned* __restrict__ row_ptr,
                                               const unsigned* __restrict__ blockOff,
                                               const unsigned* __restrict__ indeg,
                                               const _Float16* __restrict__ sfeat,
                                               const float* __restrict__ outnorm,
                                               const float* __restrict__ innorm,
                                               const int* __restrict__ gid,
                                               const _Float16* __restrict__ Wt,
                                               const float* __restrict__ b,
                                               float* __restrict__ pooled) {
    __shared__ _Float16 aggL[NPBM * DIM];   // 16 KB, XOR-swizzled rows
    __shared__ float red[4][2][DIM];        // 4 KB
    int tid = threadIdx.x;
    int lane = tid & 63, wave = tid >> 6;
    int gl = lane & 15;                     // lane within 16-group
    int gb = lane & 48;                     // group's base lane in wave
    int grp = tid >> 4;                     // 0..15 group id in block
    int blockBase = blockIdx.x * NPBM;
    int d8 = gl * 8;

    // ---- gather phase: each 16-lane group owns 4 consecutive rows ----
#pragma unroll 1
    for (int rr = 0; rr < 4; ++rr) {
        int row = grp * 4 + rr;
        int node = blockBase + row;
        float4 accA = {0,0,0,0}, accB = {0,0,0,0};
        float4 accC = {0,0,0,0}, accD = {0,0,0,0};
        float innrm = 0.f;
        if (node < N_NODES) {
            unsigned start = row_ptr[node] + blockOff[node >> 8];
            unsigned deg   = indeg[node];
            innrm = innorm[node];
            unsigned j0 = 0;
            // fast path: full 16-edge chunks, constant bounds -> 16 loads in flight
            for (; j0 + 16 <= deg; j0 += 16) {
                int sIdx = bsrc[start + j0 + (unsigned)gl];
#pragma unroll
                for (int j = 0; j < 16; j += 4) {
                    int s0 = __shfl(sIdx, gb + j);
                    int s1 = __shfl(sIdx, gb + j + 1);
                    int s2 = __shfl(sIdx, gb + j + 2);
                    int s3 = __shfl(sIdx, gb + j + 3);
                    float m0 = outnorm[s0];
                    float m1 = outnorm[s1];
                    float m2 = outnorm[s2];
                    float m3 = outnorm[s3];
                    h8 r0 = *reinterpret_cast<const h8*>(sfeat + (size_t)s0 * DIM + d8);
                    h8 r1 = *reinterpret_cast<const h8*>(sfeat + (size_t)s1 * DIM + d8);
                    h8 r2 = *reinterpret_cast<const h8*>(sfeat + (size_t)s2 * DIM + d8);
                    h8 r3 = *reinterpret_cast<const h8*>(sfeat + (size_t)s3 * DIM + d8);
                    CVT8(accA, accB, r0, m0);
                    CVT8(accC, accD, r1, m1);
                    CVT8(accA, accB, r2, m2);
                    CVT8(accC, accD, r3, m3);
                }
            }
            unsigned cnt = deg - j0;          // tail: 0..15 edges, masked
            if (cnt) {
                int sIdx = bsrc[start + j0 + ((unsigned)gl < cnt ? (unsigned)gl : 0u)];
                for (unsigned j = 0; j < cnt; j += 4) {
                    unsigned j1 = j + 1, j2 = j + 2, j3 = j + 3;
                    int s0 = __shfl(sIdx, gb + (int)j);
                    int s1 = __shfl(sIdx, gb + (int)(j1 < cnt ? j1 : 0u));
                    int s2 = __shfl(sIdx, gb + (int)(j2 < cnt ? j2 : 0u));
                    int s3 = __shfl(sIdx, gb + (int)(j3 < cnt ? j3 : 0u));
                    float m0 = outnorm[s0];
                    float m1 = (j1 < cnt) ? outnorm[s1] : 0.f;
                    float m2 = (j2 < cnt) ? outnorm[s2] : 0.f;
                    float m3 = (j3 < cnt) ? outnorm[s3] : 0.f;
                    h8 r0 = *reinterpret_cast<const h8*>(sfeat + (size_t)s0 * DIM + d8);
                    h8 r1 = *reinterpret_cast<const h8*>(sfeat + (size_t)s1 * DIM + d8);
                    h8 r2 = *reinterpret_cast<const h8*>(sfeat + (size_t)s2 * DIM + d8);
                    h8 r3 = *reinterpret_cast<const h8*>(sfeat + (size_t)s3 * DIM + d8);
                    CVT8(accA, accB, r0, m0);
                    CVT8(accC, accD, r1, m1);
                    CVT8(accA, accB, r2, m2);
                    CVT8(accC, accD, r3, m3);
                }
            }
        }
        accA.x += accC.x; accA.y += accC.y; accA.z += accC.z; accA.w += accC.w;
        accB.x += accD.x; accB.y += accD.y; accB.z += accD.z; accB.w += accD.w;
        h8 r;
        r[0] = (_Float16)(accA.x * innrm); r[1] = (_Float16)(accA.y * innrm);
        r[2] = (_Float16)(accA.z * innrm); r[3] = (_Float16)(accA.w * innrm);
        r[4] = (_Float16)(accB.x * innrm); r[5] = (_Float16)(accB.y * innrm);
        r[6] = (_Float16)(accB.z * innrm); r[7] = (_Float16)(accB.w * innrm);
        int slot = gl ^ (row & 7);          // XOR swizzle: conflict-free MFMA reads
        *reinterpret_cast<h8*>(&aggL[row * DIM + slot * 8]) = r;
    }
    __syncthreads();

    // ---- MFMA phase: wave w owns rows w*16..w*16+15 ----
    int quad = lane >> 4, m = lane & 15;
    int lrow = wave * 16;
    int gfirst = gid[blockBase];
    int gsec = gfirst + 1;

    f4v acc[8];
#pragma unroll
    for (int t = 0; t < 8; ++t) acc[t] = (f4v){0,0,0,0};

#pragma unroll
    for (int kk = 0; kk < 4; ++kk) {
        int ko = kk * 32 + quad * 8;
        int r0 = lrow + m;
        int slot0 = (kk * 4 + quad) ^ (r0 & 7);
        h8 a0 = *reinterpret_cast<const h8*>(&aggL[r0 * DIM + slot0 * 8]);
#pragma unroll
        for (int t = 0; t < 8; ++t) {
            h8 bf = *reinterpret_cast<const h8*>(Wt + (size_t)(t * 16 + m) * DIM + ko);
            acc[t] = __builtin_amdgcn_mfma_f32_16x16x32_f16(a0, bf, acc[t], 0, 0, 0);
        }
    }

    int n0 = blockBase + lrow + quad * 4;
    float s0[8], s1[8];
#pragma unroll
    for (int t = 0; t < 8; ++t) {
        float bb = b[t * 16 + m];
        s0[t] = 0.f; s1[t] = 0.f;
#pragma unroll
        for (int r = 0; r < 4; ++r) {
            int node = n0 + r;
            if (node < N_NODES) {
                float h = fmaxf(acc[t][r] + bb, 0.f);
                int g = gid[node];
                if (g == gfirst)      s0[t] += h;
                else if (g == gsec)   s1[t] += h;
                else atomicAdd(&pooled[(size_t)g * DIM + t * 16 + m], h);
            }
        }
        s0[t] += __shfl_down(s0[t], 32);
        s0[t] += __shfl_down(s0[t], 16);
        s1[t] += __shfl_down(s1[t], 32);
        s1[t] += __shfl_down(s1[t], 16);
    }
    if (quad == 0) {
#pragma unroll
        for (int t = 0; t < 8; ++t) {
            red[wave][0][t * 16 + m] = s0[t];
            red[wave][1][t * 16 + m] = s1[t];
        }
    }
    __syncthreads();
    if (tid < DIM) {
        float v0 = red[0][0][tid] + red[1][0][tid] + red[2][0][tid] + red[3][0][tid];
        if (v0 != 0.f) atomicAdd(&pooled[(size_t)gfirst * DIM + tid], v0);
        float v1 = red[0][1][tid] + red[1][1][tid] + red[2][1][tid] + red[3][1][tid];
        if (v1 != 0.f && gsec < N_GRAPHS) atomicAdd(&pooled[(size_t)gsec * DIM + tid], v1);
    }
}

// ---- head: out = (pooled/cnt) @ W_head + b_head -----------------------------
__global__ __launch_bounds__(256) void k_head(const float* __restrict__ pooled,
                                              const int* __restrict__ start,
                                              const float* __restrict__ Wh,
                                              const float* __restrict__ bh,
                                              float* __restrict__ out) {
    int i = blockIdx.x * 256 + threadIdx.x;
    if (i >= N_GRAPHS * N_CLASSES) return;
    int g = i / N_CLASSES, c = i % N_CLASSES;
    const float* pr = pooled + g * DIM;
    float s = 0.f;
#pragma unroll 8
    for (int k = 0; k < DIM; ++k) s += pr[k] * Wh[k * N_CLASSES + c];
    float cntf = fmaxf((float)(start[g + 1] - start[g]), 1.0f);
    out[i] = s / cntf + bh[c];
}

extern "C" void kernel_launch(void* const* d_in, const int* in_sizes, int n_in,
                              void* d_out, int out_size, void* d_ws, size_t ws_size,
                              hipStream_t stream) {
    const float* feat = (const float*)d_in[0];
    const int*   src  = (const int*)d_in[1];
    const int*   dst  = (const int*)d_in[2];
    const int*   gid  = (const int*)d_in[3];
    const float* W    = (const float*)d_in[4];
    const float* b    = (const float*)d_in[5];
    const float* Wh   = (const float*)d_in[6];
    const float* bh   = (const float*)d_in[7];
    float* out = (float*)d_out;

    // ---- workspace layout (4-byte elements; 16B-aligned regions) ----
    float*    pooled   = (float*)d_ws;                                  // G*D
    unsigned* indeg    = (unsigned*)(pooled + (size_t)N_GRAPHS * DIM);  // N
    float*    outnorm  = (float*)(indeg + N_NODES);                     // N
    float*    innorm   = outnorm + N_NODES;                             // N
    int*      start    = (int*)(innorm + N_NODES);                      // G+1 (pad to 128)
    unsigned* row_ptr  = (unsigned*)(start + 128);                      // N
    unsigned* blockSums= row_ptr + N_NODES;                             // 256
    unsigned* blockOff = blockSums + 256;                               // 256
    unsigned char* perm= (unsigned char*)(blockOff + 256);              // E bytes
    unsigned short* bsrc = (unsigned short*)(perm + N_EDGES);           // E u16
    _Float16* sfeat    = (_Float16*)(bsrc + N_EDGES);                   // N*D halves
    _Float16* aggh     = sfeat + (size_t)N_NODES * DIM;                 // (unused now)
    _Float16* Wt       = aggh + (size_t)N_NODES * DIM;                  // DIM*DIM halves
    unsigned* Hin      = (unsigned*)(Wt + DIM * DIM);                   // NCHE*LQ
    unsigned* Hout     = Hin + (size_t)NCHE * LQ;                       // NCHE*LQ

    k_lhist <<<LH_BLKS, 256, 0, stream>>>(src, dst, Hin, Hout, perm,
                                          feat, sfeat, W, Wt);
    k_reduce<<<NBR2, 256, 0, stream>>>(Hin, Hout, gid, indeg, outnorm, innorm,
                                       start, row_ptr, blockSums);
    k_scan2 <<<1, 256, 0, stream>>>(blockSums, blockOff, pooled);
    k_place <<<PLACE_BLKS, 256, 0, stream>>>(src, dst, Hin, perm, row_ptr,
                                             blockOff, bsrc);
    k_gnode <<<NBLK_NODE, 256, 0, stream>>>(bsrc, row_ptr, blockOff, indeg,
                                            sfeat, outnorm, innorm, gid, Wt, b, pooled);
    k_head  <<<3, 256, 0, stream>>>(pooled, start, Wh, bh, out);
}

// Round 4
// 174.995 us; speedup vs baseline: 1.1085x; 1.1085x over previous
//
#include <hip/hip_runtime.h>

#define N_NODES   50000
#define N_EDGES   800000
#define DIM       128
#define N_GRAPHS  64
#define N_CLASSES 10
#define NCHE      64                   // edge chunks (u8-safe: per-chunk count <= deg ~50)
#define CSZ       (N_EDGES / NCHE)     // 12500
#define LQ        (N_NODES / 4)        // 12500 u8-packed words (4 nodes/word)
#define WPB       64                   // words per reduce block (256 nodes)
#define NBR2      ((LQ + WPB - 1) / WPB)   // 196
#define PLACE_BPC ((CSZ + 255) / 256)      // 49
#define PLACE_BLKS (NCHE * PLACE_BPC)      // 3136
#define PRES_BLKS ((N_NODES * DIM / 8 + 255) / 256)  // 3125
#define WT_BLKS   (DIM * DIM / 256)        // 64
#define LH_HIST   (2 * NCHE)               // 128 histogram blocks
#define LH_BLKS   (LH_HIST + PRES_BLKS + WT_BLKS)  // 3317
#define NPBM      128                  // nodes per block in k_node (MFMA)
#define NBLK_NODE ((N_NODES + NPBM - 1) / NPBM)  // 391

typedef _Float16 h8 __attribute__((ext_vector_type(8)));
typedef float f4v __attribute__((ext_vector_type(4)));

// ---- per-chunk LDS histograms (u8 packed) + overlapped prescale / W^T build
// hist blocks use only ~43 CUs (50KB LDS each); prescale rides the idle CUs.
__global__ __launch_bounds__(256) void k_lhist(const int* __restrict__ src,
                                               const int* __restrict__ dst,
                                               unsigned* __restrict__ Hin,
                                               unsigned* __restrict__ Hout,
                                               unsigned char* __restrict__ perm,
                                               const float* __restrict__ feat,
                                               _Float16* __restrict__ sfeat,
                                               const float* __restrict__ W,
                                               _Float16* __restrict__ Wt) {
    __shared__ unsigned L[LQ];         // 50 KB
    int blk = blockIdx.x, t = threadIdx.x;
    if (blk >= LH_HIST) {
        int q = blk - LH_HIST;
        if (q < PRES_BLKS) {
            // plain fp32 -> fp16 cast (outnorm folded into gather)
            int i = q * 256 + t;
            if (i < N_NODES * DIM / 8) {
                const float4* p = reinterpret_cast<const float4*>(feat + (size_t)i * 8);
                float4 a = p[0], qv = p[1];
                h8 r;
                r[0] = (_Float16)a.x;  r[1] = (_Float16)a.y;
                r[2] = (_Float16)a.z;  r[3] = (_Float16)a.w;
                r[4] = (_Float16)qv.x; r[5] = (_Float16)qv.y;
                r[6] = (_Float16)qv.z; r[7] = (_Float16)qv.w;
                *reinterpret_cast<h8*>(sfeat + (size_t)i * 8) = r;
            }
        } else {
            int i = (q - PRES_BLKS) * 256 + t;   // i < DIM*DIM
            int n = i >> 7, k = i & 127;
            Wt[n * DIM + k] = (_Float16)W[k * DIM + n];
        }
        return;
    }
    int c = blk & (NCHE - 1);
    int phase = blk >> 6;              // 0: dst(+perm), 1: src
    int base = c * CSZ;
    for (int w = t; w < LQ; w += 256) L[w] = 0u;
    __syncthreads();
    if (phase == 0) {
        for (int i = t; i < CSZ; i += 256) {
            int d = dst[base + i];
            int sh = (d & 3) * 8;
            unsigned old = atomicAdd(&L[d >> 2], 1u << sh);
            perm[base + i] = (unsigned char)((old >> sh) & 0xffu);
        }
        __syncthreads();
        for (int w = t; w < LQ; w += 256) Hin[(size_t)c * LQ + w] = L[w];
    } else {
        for (int i = t; i < CSZ; i += 256) {
            int s = src[base + i];
            atomicAdd(&L[s >> 2], 1u << ((s & 3) * 8));
        }
        __syncthreads();
        for (int w = t; w < LQ; w += 256) Hout[(size_t)c * LQ + w] = L[w];
    }
}

// ---- reduce: degrees/norms; Hin := per-chunk prefix; boundaries; scan p1 ----
__global__ __launch_bounds__(256) void k_reduce(unsigned* __restrict__ Hin,
                                                const unsigned* __restrict__ Hout,
                                                const int* __restrict__ gid,
                                                unsigned* __restrict__ indeg,
                                                float* __restrict__ outnorm,
                                                float* __restrict__ innorm,
                                                int* __restrict__ start,
                                                unsigned* __restrict__ row_ptr,
                                                unsigned* __restrict__ blockSums) {
    __shared__ unsigned sIn[4][WPB];
    __shared__ unsigned sOut[4][WPB];
    __shared__ unsigned sS[WPB];
    int t = threadIdx.x;
    int wl = t & (WPB - 1);
    int g  = t >> 6;
    int w  = blockIdx.x * WPB + wl;
    unsigned gs = 0, os = 0;
    int c0 = g * (NCHE / 4);
    if (w < LQ) {
        for (int c = c0; c < c0 + NCHE / 4; ++c) {
            gs += Hin[(size_t)c * LQ + w];     // u8 packed adds: no carry (deg ~50)
            os += Hout[(size_t)c * LQ + w];
        }
    }
    sIn[g][wl] = gs; sOut[g][wl] = os;
    __syncthreads();
    unsigned baseg = 0;
    for (int gg = 0; gg < 4; ++gg) if (gg < g) baseg += sIn[gg][wl];
    if (w < LQ) {
        unsigned running = baseg;
        for (int c = c0; c < c0 + NCHE / 4; ++c) {
            size_t idx = (size_t)c * LQ + w;
            unsigned word = Hin[idx];
            Hin[idx] = running;
            running += word;
        }
    }
    unsigned tot = 0, otot = 0, wtot = 0;
    if (t < WPB) {
        tot  = sIn[0][t] + sIn[1][t] + sIn[2][t] + sIn[3][t];
        otot = sOut[0][t] + sOut[1][t] + sOut[2][t] + sOut[3][t];
        wtot = (tot & 0xffu) + ((tot >> 8) & 0xffu) + ((tot >> 16) & 0xffu) + (tot >> 24);
        sS[t] = wtot;
    }
    __syncthreads();
    for (int off = 1; off < WPB; off <<= 1) {
        unsigned x = (t < WPB && t >= off) ? sS[t - off] : 0u;
        __syncthreads();
        if (t < WPB) sS[t] += x;
        __syncthreads();
    }
    if (t < WPB) {
        int ww = blockIdx.x * WPB + t;
        if (ww < LQ) {
            unsigned r0 = tot & 0xffu, r1 = (tot >> 8) & 0xffu,
                     r2 = (tot >> 16) & 0xffu, r3 = tot >> 24;
            unsigned o0 = otot & 0xffu, o1 = (otot >> 8) & 0xffu,
                     o2 = (otot >> 16) & 0xffu, o3 = otot >> 24;
            unsigned ex = sS[t] - wtot;
            int n = 4 * ww;
            row_ptr[n]     = ex;
            row_ptr[n + 1] = ex + r0;
            row_ptr[n + 2] = ex + r0 + r1;
            row_ptr[n + 3] = ex + r0 + r1 + r2;
            unsigned rr[4] = {r0, r1, r2, r3}, oo[4] = {o0, o1, o2, o3};
#pragma unroll
            for (int j = 0; j < 4; ++j) {
                indeg[n + j]   = rr[j];
                innorm[n + j]  = rsqrtf(fmaxf((float)rr[j], 1.0f));
                outnorm[n + j] = rsqrtf(fmaxf((float)oo[j], 1.0f));
                int i = n + j;
                int gq = gid[i];
                if (i == 0) {
                    for (int x2 = 0; x2 <= gq; ++x2) start[x2] = 0;
                } else {
                    int gp = gid[i - 1];
                    if (gp != gq)
                        for (int x2 = gp + 1; x2 <= gq; ++x2) start[x2] = i;
                }
                if (i == N_NODES - 1)
                    for (int x2 = gq + 1; x2 <= N_GRAPHS; ++x2) start[x2] = N_NODES;
            }
        }
        if (t == WPB - 1) blockSums[blockIdx.x] = sS[WPB - 1];
    }
}

// ---- scan pass 2 + pooled zeroing ------------------------------------------
__global__ __launch_bounds__(256) void k_scan2(unsigned* __restrict__ blockSums,
                                               unsigned* __restrict__ blockOff,
                                               float* __restrict__ pooled) {
    __shared__ unsigned s[256];
    int t = threadIdx.x;
    unsigned val = (t < NBR2) ? blockSums[t] : 0u;
    s[t] = val;
    __syncthreads();
    for (int off = 1; off < 256; off <<= 1) {
        unsigned x = (t >= off) ? s[t - off] : 0u;
        __syncthreads();
        s[t] += x;
        __syncthreads();
    }
    if (t < NBR2) blockOff[t] = s[t] - val;
    float4 z = {0.f, 0.f, 0.f, 0.f};
    for (int i = t; i < N_GRAPHS * DIM / 4; i += 256)
        reinterpret_cast<float4*>(pooled)[i] = z;
}

// ---- CSR place (u16 bsrc) ---------------------------------------------------
__global__ __launch_bounds__(256) void k_place(const int* __restrict__ src,
                                               const int* __restrict__ dst,
                                               const unsigned* __restrict__ Hin,
                                               const unsigned char* __restrict__ perm,
                                               const unsigned* __restrict__ row_ptr,
                                               const unsigned* __restrict__ blockOff,
                                               unsigned short* __restrict__ bsrc) {
    int t = threadIdx.x;
    int blk = blockIdx.x;
    int c = blk / PLACE_BPC;
    int i = (blk % PLACE_BPC) * 256 + t;
    if (i < CSZ) {
        int e = c * CSZ + i;
        int d = dst[e];
        int sh = (d & 3) * 8;
        unsigned pre = (Hin[(size_t)c * LQ + (d >> 2)] >> sh) & 0xffu;
        unsigned pos = row_ptr[d] + blockOff[d >> 8] + pre + perm[e];
        bsrc[pos] = (unsigned short)src[e];
    }
}

#define CVT8(ACC_A, ACC_B, R, M) \
    ACC_A.x += (M) * (float)R[0]; ACC_A.y += (M) * (float)R[1]; \
    ACC_A.z += (M) * (float)R[2]; ACC_A.w += (M) * (float)R[3]; \
    ACC_B.x += (M) * (float)R[4]; ACC_B.y += (M) * (float)R[5]; \
    ACC_B.z += (M) * (float)R[6]; ACC_B.w += (M) * (float)R[7];

// ---- gather-sum over fp16 rows, outnorm folded as multiplier; 1 node/wave ---
// 12500 blocks = 50000 waves: full latency hiding for the random sfeat reads.
__global__ __launch_bounds__(256) void k_gather(const unsigned short* __restrict__ bsrc,
                                                const unsigned* __restrict__ row_ptr,
                                                const unsigned* __restrict__ blockOff,
                                                const unsigned* __restrict__ indeg,
                                                const _Float16* __restrict__ sfeat,
                                                const float* __restrict__ outnorm,
                                                const float* __restrict__ innorm,
                                                _Float16* __restrict__ aggh) {
    int tid = threadIdx.x;
    int wave = tid >> 6;
    int lane = tid & 63;
    int node = blockIdx.x * 4 + wave;
    if (node >= N_NODES) return;
    unsigned start = row_ptr[node] + blockOff[node >> 8];
    unsigned deg   = indeg[node];
    unsigned lim   = deg < 64u ? deg : 64u;
    int qtr = lane >> 4;
    int d8  = (lane & 15) << 3;
    int sIdx = 0;
    if ((unsigned)lane < lim) sIdx = bsrc[start + lane];
    float4 accA = {0,0,0,0}, accB = {0,0,0,0};
    float4 accC = {0,0,0,0}, accD = {0,0,0,0};
    for (unsigned j = 0; j < lim; j += 16) {
        unsigned j0 = j + qtr, j1 = j + 4 + qtr, j2 = j + 8 + qtr, j3 = j + 12 + qtr;
        int s0 = __shfl(sIdx, (int)(j0 < lim ? j0 : 0u));
        int s1 = __shfl(sIdx, (int)(j1 < lim ? j1 : 0u));
        int s2 = __shfl(sIdx, (int)(j2 < lim ? j2 : 0u));
        int s3 = __shfl(sIdx, (int)(j3 < lim ? j3 : 0u));
        float m0 = (j0 < lim) ? outnorm[s0] : 0.f;
        float m1 = (j1 < lim) ? outnorm[s1] : 0.f;
        float m2 = (j2 < lim) ? outnorm[s2] : 0.f;
        float m3 = (j3 < lim) ? outnorm[s3] : 0.f;
        h8 r0 = *reinterpret_cast<const h8*>(sfeat + (size_t)s0 * DIM + d8);
        h8 r1 = *reinterpret_cast<const h8*>(sfeat + (size_t)s1 * DIM + d8);
        h8 r2 = *reinterpret_cast<const h8*>(sfeat + (size_t)s2 * DIM + d8);
        h8 r3 = *reinterpret_cast<const h8*>(sfeat + (size_t)s3 * DIM + d8);
        CVT8(accA, accB, r0, m0);
        CVT8(accC, accD, r1, m1);
        CVT8(accA, accB, r2, m2);
        CVT8(accC, accD, r3, m3);
    }
    for (unsigned j = 64; j < deg; j += 4) {   // overflow: deg > 64 (rare)
        unsigned jj = j + qtr;
        bool valid = jj < deg;
        int s = bsrc[start + (valid ? jj : 0u)];
        float m = valid ? outnorm[s] : 0.f;
        h8 r = *reinterpret_cast<const h8*>(sfeat + (size_t)s * DIM + d8);
        CVT8(accA, accB, r, m);
    }
    accA.x += accC.x; accA.y += accC.y; accA.z += accC.z; accA.w += accC.w;
    accB.x += accD.x; accB.y += accD.y; accB.z += accD.z; accB.w += accD.w;
    accA.x += __shfl_down(accA.x, 32); accA.y += __shfl_down(accA.y, 32);
    accA.z += __shfl_down(accA.z, 32); accA.w += __shfl_down(accA.w, 32);
    accB.x += __shfl_down(accB.x, 32); accB.y += __shfl_down(accB.y, 32);
    accB.z += __shfl_down(accB.z, 32); accB.w += __shfl_down(accB.w, 32);
    accA.x += __shfl_down(accA.x, 16); accA.y += __shfl_down(accA.y, 16);
    accA.z += __shfl_down(accA.z, 16); accA.w += __shfl_down(accA.w, 16);
    accB.x += __shfl_down(accB.x, 16); accB.y += __shfl_down(accB.y, 16);
    accB.z += __shfl_down(accB.z, 16); accB.w += __shfl_down(accB.w, 16);
    if (qtr == 0) {
        float innrm = innorm[node];
        h8 r;
        r[0] = (_Float16)(accA.x * innrm); r[1] = (_Float16)(accA.y * innrm);
        r[2] = (_Float16)(accA.z * innrm); r[3] = (_Float16)(accA.w * innrm);
        r[4] = (_Float16)(accB.x * innrm); r[5] = (_Float16)(accB.y * innrm);
        r[6] = (_Float16)(accB.z * innrm); r[7] = (_Float16)(accB.w * innrm);
        *reinterpret_cast<h8*>(aggh + (size_t)node * DIM + d8) = r;
    }
}

// ---- node transform via MFMA + fused mean-pool ------------------------------
__global__ __launch_bounds__(256) void k_node(const _Float16* __restrict__ aggh,
                                              const int* __restrict__ gid,
                                              const _Float16* __restrict__ Wt,
                                              const float* __restrict__ b,
                                              float* __restrict__ pooled) {
    __shared__ float red[4][2][DIM];   // 4 KB
    int tid = threadIdx.x;
    int wave = tid >> 6, lane = tid & 63;
    int quad = lane >> 4, m = lane & 15;
    int blockBase = blockIdx.x * NPBM;
    int wbase = blockBase + wave * 32;
    int gfirst = gid[blockBase];
    int gsec = gfirst + 1;

    f4v acc0[8], acc1[8];
#pragma unroll
    for (int t = 0; t < 8; ++t) { acc0[t] = (f4v){0,0,0,0}; acc1[t] = (f4v){0,0,0,0}; }

#pragma unroll
    for (int kk = 0; kk < 4; ++kk) {
        int ko = kk * 32 + quad * 8;
        h8 a0 = *reinterpret_cast<const h8*>(aggh + (size_t)(wbase + m) * DIM + ko);
        h8 a1 = *reinterpret_cast<const h8*>(aggh + (size_t)(wbase + 16 + m) * DIM + ko);
#pragma unroll
        for (int t = 0; t < 8; ++t) {
            h8 bf = *reinterpret_cast<const h8*>(Wt + (size_t)(t * 16 + m) * DIM + ko);
            acc0[t] = __builtin_amdgcn_mfma_f32_16x16x32_f16(a0, bf, acc0[t], 0, 0, 0);
            acc1[t] = __builtin_amdgcn_mfma_f32_16x16x32_f16(a1, bf, acc1[t], 0, 0, 0);
        }
    }

    int n0 = wbase + quad * 4;
    int n1 = n0 + 16;
    float s0[8], s1[8];
#pragma unroll
    for (int t = 0; t < 8; ++t) {
        float bb = b[t * 16 + m];
        s0[t] = 0.f; s1[t] = 0.f;
#pragma unroll
        for (int r = 0; r < 4; ++r) {
            int node = n0 + r;
            if (node < N_NODES) {
                float h = fmaxf(acc0[t][r] + bb, 0.f);
                int g = gid[node];
                if (g == gfirst)      s0[t] += h;
                else if (g == gsec)   s1[t] += h;
                else atomicAdd(&pooled[(size_t)g * DIM + t * 16 + m], h);
            }
            int node2 = n1 + r;
            if (node2 < N_NODES) {
                float h = fmaxf(acc1[t][r] + bb, 0.f);
                int g = gid[node2];
                if (g == gfirst)      s0[t] += h;
                else if (g == gsec)   s1[t] += h;
                else atomicAdd(&pooled[(size_t)g * DIM + t * 16 + m], h);
            }
        }
        s0[t] += __shfl_down(s0[t], 32);
        s0[t] += __shfl_down(s0[t], 16);
        s1[t] += __shfl_down(s1[t], 32);
        s1[t] += __shfl_down(s1[t], 16);
    }
    if (quad == 0) {
#pragma unroll
        for (int t = 0; t < 8; ++t) {
            red[wave][0][t * 16 + m] = s0[t];
            red[wave][1][t * 16 + m] = s1[t];
        }
    }
    __syncthreads();
    if (tid < DIM) {
        float v0 = red[0][0][tid] + red[1][0][tid] + red[2][0][tid] + red[3][0][tid];
        if (v0 != 0.f) atomicAdd(&pooled[(size_t)gfirst * DIM + tid], v0);
        float v1 = red[0][1][tid] + red[1][1][tid] + red[2][1][tid] + red[3][1][tid];
        if (v1 != 0.f && gsec < N_GRAPHS) atomicAdd(&pooled[(size_t)gsec * DIM + tid], v1);
    }
}

// ---- head: out = (pooled/cnt) @ W_head + b_head -----------------------------
__global__ __launch_bounds__(256) void k_head(const float* __restrict__ pooled,
                                              const int* __restrict__ start,
                                              const float* __restrict__ Wh,
                                              const float* __restrict__ bh,
                                              float* __restrict__ out) {
    int i = blockIdx.x * 256 + threadIdx.x;
    if (i >= N_GRAPHS * N_CLASSES) return;
    int g = i / N_CLASSES, c = i % N_CLASSES;
    const float* pr = pooled + g * DIM;
    float s = 0.f;
#pragma unroll 8
    for (int k = 0; k < DIM; ++k) s += pr[k] * Wh[k * N_CLASSES + c];
    float cntf = fmaxf((float)(start[g + 1] - start[g]), 1.0f);
    out[i] = s / cntf + bh[c];
}

extern "C" void kernel_launch(void* const* d_in, const int* in_sizes, int n_in,
                              void* d_out, int out_size, void* d_ws, size_t ws_size,
                              hipStream_t stream) {
    const float* feat = (const float*)d_in[0];
    const int*   src  = (const int*)d_in[1];
    const int*   dst  = (const int*)d_in[2];
    const int*   gid  = (const int*)d_in[3];
    const float* W    = (const float*)d_in[4];
    const float* b    = (const float*)d_in[5];
    const float* Wh   = (const float*)d_in[6];
    const float* bh   = (const float*)d_in[7];
    float* out = (float*)d_out;

    // ---- workspace layout (4-byte elements; 16B-aligned regions) ----
    float*    pooled   = (float*)d_ws;                                  // G*D
    unsigned* indeg    = (unsigned*)(pooled + (size_t)N_GRAPHS * DIM);  // N
    float*    outnorm  = (float*)(indeg + N_NODES);                     // N
    float*    innorm   = outnorm + N_NODES;                             // N
    int*      start    = (int*)(innorm + N_NODES);                      // G+1 (pad to 128)
    unsigned* row_ptr  = (unsigned*)(start + 128);                      // N
    unsigned* blockSums= row_ptr + N_NODES;                             // 256
    unsigned* blockOff = blockSums + 256;                               // 256
    unsigned char* perm= (unsigned char*)(blockOff + 256);              // E bytes
    unsigned short* bsrc = (unsigned short*)(perm + N_EDGES);           // E u16
    _Float16* sfeat    = (_Float16*)(bsrc + N_EDGES);                   // N*D halves
    _Float16* aggh     = sfeat + (size_t)N_NODES * DIM;                 // N*D halves
    _Float16* Wt       = aggh + (size_t)N_NODES * DIM;                  // DIM*DIM halves
    unsigned* Hin      = (unsigned*)(Wt + DIM * DIM);                   // NCHE*LQ
    unsigned* Hout     = Hin + (size_t)NCHE * LQ;                       // NCHE*LQ

    k_lhist <<<LH_BLKS, 256, 0, stream>>>(src, dst, Hin, Hout, perm,
                                          feat, sfeat, W, Wt);
    k_reduce<<<NBR2, 256, 0, stream>>>(Hin, Hout, gid, indeg, outnorm, innorm,
                                       start, row_ptr, blockSums);
    k_scan2 <<<1, 256, 0, stream>>>(blockSums, blockOff, pooled);
    k_place <<<PLACE_BLKS, 256, 0, stream>>>(src, dst, Hin, perm, row_ptr,
                                             blockOff, bsrc);
    k_gather<<<(N_NODES + 3) / 4, 256, 0, stream>>>(bsrc, row_ptr, blockOff, indeg,
                                                    sfeat, outnorm, innorm, aggh);
    k_node  <<<NBLK_NODE, 256, 0, stream>>>(aggh, gid, Wt, b, pooled);
    k_head  <<<3, 256, 0, stream>>>(pooled, start, Wh, bh, out);
}